// Round 1
// baseline (276.771 us; speedup 1.0000x reference)
//
#include <hip/hip_runtime.h>
#include <math.h>

// TopKMoEGate via split-bf16 MFMA:
//   x = xh + xl, W = wh + wl (bf16 hi/lo); logits = xh*wh + xh*wl + xl*wh
//   (fp32-accurate to ~5e-6; wave-parallel fp64 tie-guard on top-3 candidates).
// R8: barrier-free register-fragment K-loop. The R7 kernel was latency-bound
//     (occupancy 17%, MfmaUtil 5.6%, 64 KB LDS -> 2 blocks/CU, 1 barrier per
//     chunk). MFMA A/B fragments are fed directly from global: x as 2x float4
//     per lane (split2 in-register), W from the pre-converted bf16 planes
//     (L2-resident). No main-loop LDS, no main-loop barriers, zero bank
//     conflicts. Per 16-token tile, 4 waves split 2-way experts x 2-way K;
//     one small LDS combine + the verified lane=expert epilogue at the end.
//     Grid 1024 blocks x 256 thr -> 4 blocks/CU = 16 waves/CU.
// Distance-1 prefetch via EXPLICIT unroll-by-2 with two named register sets
// (never index register arrays dynamically -> scratch).

typedef __attribute__((ext_vector_type(8))) __bf16 bf16x8;
typedef __attribute__((ext_vector_type(8))) unsigned short u16x8;
typedef __attribute__((ext_vector_type(4))) float f32x4;

constexpr int EXPN = 64;   // experts
constexpr int TM   = 16;   // tokens per block (one 16-row MFMA tile)

__device__ __forceinline__ void split2(float f, unsigned short& h, unsigned short& l) {
    const unsigned b = __float_as_uint(f);
    h = (unsigned short)(b >> 16);                       // bf16 hi (truncate)
    const float fh = __uint_as_float(b & 0xffff0000u);
    l = (unsigned short)(__float_as_uint(f - fh) >> 16); // bf16 lo
}

__device__ __forceinline__ bf16x8 as_bf16(u16x8 v) {
    union { u16x8 u; bf16x8 b; } c; c.u = v; return c.b;
}

// ---- pre-kernel: W fp32 -> wh/wl bf16 planes (same split2 numerics) ----
__global__ __launch_bounds__(256)
void convert_w_kernel(const float* __restrict__ W,
                      unsigned short* __restrict__ whp,
                      unsigned short* __restrict__ wlp, int n4)
{
    const int i = blockIdx.x * 256 + threadIdx.x;   // float4 index
    if (i >= n4) return;
    const float4 v = *(const float4*)(W + (size_t)i * 4);
    const float f[4] = {v.x, v.y, v.z, v.w};
    unsigned short h[4], l[4];
#pragma unroll
    for (int j = 0; j < 4; ++j) split2(f[j], h[j], l[j]);
    *(ushort4*)(whp + (size_t)i * 4) = make_ushort4(h[0], h[1], h[2], h[3]);
    *(ushort4*)(wlp + (size_t)i * 4) = make_ushort4(l[0], l[1], l[2], l[3]);
}

__global__ __launch_bounds__(256, 4)
void moe_gate_kernel(const float* __restrict__ x,      // [M, D]
                     const float* __restrict__ W,      // [E, D] (fp64 guard only)
                     const unsigned short* __restrict__ whp,  // [E, D] bf16 hi
                     const unsigned short* __restrict__ wlp,  // [E, D] bf16 lo
                     const float* __restrict__ nw,     // [E]
                     const float* __restrict__ noise,  // [M, E]
                     float* __restrict__ probs,        // [M, E]
                     float* __restrict__ idx_out,      // [M, 2] float-encoded
                     float* __restrict__ val_out,      // [M, 2]
                     int D)
{
    __shared__ float ps[TM][EXPN + 1];   // kh=1 partial logits (4.2 KB)
    __shared__ float ls[TM][EXPN + 1];   // final logits        (4.2 KB)

    const int tid  = threadIdx.x;
    const int lane = tid & 63;
    const int wv   = tid >> 6;
    const int eh   = wv & 1;        // expert half: experts [eh*32, eh*32+32)
    const int kh   = wv >> 1;       // K half:      k in [kh*D/2, (kh+1)*D/2)
    const int m0   = blockIdx.x * TM;

    const int fr = lane & 15;           // A row (token) / B row (expert) in frag
    const int kq = (lane >> 4) * 8;     // k sub-offset in frag
    const int khalf = D >> 1;           // 1024
    const int k0 = kh * khalf;

    // per-lane fragment base pointers (all 16B-aligned)
    const float*          xb  = x   + (size_t)(m0 + fr) * D + k0 + kq;
    const unsigned short* wh0 = whp + (size_t)(eh * 32 + fr)      * D + k0 + kq;
    const unsigned short* wh1 = whp + (size_t)(eh * 32 + 16 + fr) * D + k0 + kq;
    const unsigned short* wl0 = wlp + (size_t)(eh * 32 + fr)      * D + k0 + kq;
    const unsigned short* wl1 = wlp + (size_t)(eh * 32 + 16 + fr) * D + k0 + kq;

    f32x4 acc0 = {0.f, 0.f, 0.f, 0.f};   // experts eh*32 + [0,16)
    f32x4 acc1 = {0.f, 0.f, 0.f, 0.f};   // experts eh*32 + [16,32)

    // two named prefetch sets: A = even 32-chunk, B = odd 32-chunk
    float4 ax0, ax1, bx0, bx1;
    u16x8  a0h, a0l, a1h, a1l, b0h, b0l, b1h, b1l;

#define LOAD_SET(X0, X1, H0, L0, H1, L1, ko)                            \
    X0 = *(const float4*)(xb  + (ko));                                  \
    X1 = *(const float4*)(xb  + (ko) + 4);                              \
    H0 = *(const u16x8*)(wh0 + (ko));                                   \
    L0 = *(const u16x8*)(wl0 + (ko));                                   \
    H1 = *(const u16x8*)(wh1 + (ko));                                   \
    L1 = *(const u16x8*)(wl1 + (ko));

#define COMPUTE(X0, X1, H0, L0, H1, L1)                                 \
    {                                                                   \
        const float xf_[8] = {X0.x, X0.y, X0.z, X0.w,                   \
                              X1.x, X1.y, X1.z, X1.w};                  \
        u16x8 hv_, lv_;                                                 \
        _Pragma("unroll")                                               \
        for (int i_ = 0; i_ < 8; ++i_) {                                \
            unsigned short a_, b_; split2(xf_[i_], a_, b_);             \
            hv_[i_] = a_; lv_[i_] = b_;                                 \
        }                                                               \
        const bf16x8 ah_ = as_bf16(hv_), al_ = as_bf16(lv_);            \
        acc0 = __builtin_amdgcn_mfma_f32_16x16x32_bf16(ah_, as_bf16(H0), acc0, 0, 0, 0); \
        acc0 = __builtin_amdgcn_mfma_f32_16x16x32_bf16(ah_, as_bf16(L0), acc0, 0, 0, 0); \
        acc0 = __builtin_amdgcn_mfma_f32_16x16x32_bf16(al_, as_bf16(H0), acc0, 0, 0, 0); \
        acc1 = __builtin_amdgcn_mfma_f32_16x16x32_bf16(ah_, as_bf16(H1), acc1, 0, 0, 0); \
        acc1 = __builtin_amdgcn_mfma_f32_16x16x32_bf16(ah_, as_bf16(L1), acc1, 0, 0, 0); \
        acc1 = __builtin_amdgcn_mfma_f32_16x16x32_bf16(al_, as_bf16(H1), acc1, 0, 0, 0); \
    }

    LOAD_SET(ax0, ax1, a0h, a0l, a1h, a1l, 0)
    LOAD_SET(bx0, bx1, b0h, b0l, b1h, b1l, 32)

    for (int ks = 0; ks < khalf; ks += 64) {
        COMPUTE(ax0, ax1, a0h, a0l, a1h, a1l)
        if (ks + 64 < khalf) {
            LOAD_SET(ax0, ax1, a0h, a0l, a1h, a1l, ks + 64)
        }
        COMPUTE(bx0, bx1, b0h, b0l, b1h, b1l)
        if (ks + 96 < khalf) {
            LOAD_SET(bx0, bx1, b0h, b0l, b1h, b1l, ks + 96)
        }
    }

#undef LOAD_SET
#undef COMPUTE

    // ---- combine K halves (C/D layout: col = lane&15, row = (lane>>4)*4+reg) ----
    const int trow = (lane >> 4) * 4;
    if (kh == 1) {
#pragma unroll
        for (int r = 0; r < 4; ++r) {
            ps[trow + r][eh * 32 + fr]      = acc0[r];
            ps[trow + r][eh * 32 + 16 + fr] = acc1[r];
        }
    }
    __syncthreads();
    if (kh == 0) {
#pragma unroll
        for (int r = 0; r < 4; ++r) {
            ls[trow + r][eh * 32 + fr]      = acc0[r] + ps[trow + r][eh * 32 + fr];
            ls[trow + r][eh * 32 + 16 + fr] = acc1[r] + ps[trow + r][eh * 32 + 16 + fr];
        }
    }
    __syncthreads();

    // ---- epilogue: per-token noisy top-2 + sparse softmax (lane = expert) ----
    const float nwv = nw[lane];

#pragma unroll 1
    for (int t = 0; t < 4; ++t) {
        const int tl = wv * 4 + t;       // local token
        const int g  = m0 + tl;          // global token
        const float logit = fmaf(noise[(size_t)g * EXPN + lane], nwv, ls[tl][lane]);

        float v0; int i0;
        {
            float v = logit; int ix = lane;
#pragma unroll
            for (int off = 32; off; off >>= 1) {
                const float vo = __shfl_xor(v, off);
                const int   io = __shfl_xor(ix, off);
                if (vo > v || (vo == v && io < ix)) { v = vo; ix = io; }
            }
            v0 = v; i0 = ix;
        }
        float v1; int i1;
        {
            float v = (lane == i0) ? -INFINITY : logit; int ix = lane;
#pragma unroll
            for (int off = 32; off; off >>= 1) {
                const float vo = __shfl_xor(v, off);
                const int   io = __shfl_xor(ix, off);
                if (vo > v || (vo == v && io < ix)) { v = vo; ix = io; }
            }
            v1 = v; i1 = ix;
        }
        float v2; int i2;
        {
            float v = (lane == i0 || lane == i1) ? -INFINITY : logit; int ix = lane;
#pragma unroll
            for (int off = 32; off; off >>= 1) {
                const float vo = __shfl_xor(v, off);
                const int   io = __shfl_xor(ix, off);
                if (vo > v || (vo == v && io < ix)) { v = vo; ix = io; }
            }
            v2 = v; i2 = ix;
        }

        // near-tie guard: wave-parallel fp64 recompute of the 3 candidate
        // logits (lanes stride K by 64 -> coalesced; butterfly fp64 sum).
        const float eps = 1e-3f;
        if ((v0 - v1) < eps || (v1 - v2) < eps) {
            const float* xr  = x + (size_t)g * D;
            const float* w0r = W + (size_t)i0 * D;
            const float* w1r = W + (size_t)i1 * D;
            const float* w2r = W + (size_t)i2 * D;
            double s0 = 0.0, s1 = 0.0, s2 = 0.0;
            for (int d = lane; d < D; d += 64) {
                const double xv = (double)xr[d];
                s0 += xv * (double)w0r[d];
                s1 += xv * (double)w1r[d];
                s2 += xv * (double)w2r[d];
            }
#pragma unroll
            for (int off = 32; off; off >>= 1) {
                s0 += __shfl_xor(s0, off);
                s1 += __shfl_xor(s1, off);
                s2 += __shfl_xor(s2, off);
            }
            double d0 = s0 + (double)noise[(size_t)g * EXPN + i0] * (double)nw[i0];
            double d1 = s1 + (double)noise[(size_t)g * EXPN + i1] * (double)nw[i1];
            double d2 = s2 + (double)noise[(size_t)g * EXPN + i2] * (double)nw[i2];
            // sort 3 (value desc, index asc on ties)
            #define CSWAP(va, ia, vb, ib)                                   \
                if ((vb > va) || (vb == va && ib < ia)) {                   \
                    double tv = va; va = vb; vb = tv;                       \
                    int ti = ia; ia = ib; ib = ti; }
            CSWAP(d0, i0, d1, i1)
            CSWAP(d1, i1, d2, i2)
            CSWAP(d0, i0, d1, i1)
            #undef CSWAP
            v0 = (float)d0; v1 = (float)d1;
        }

        const float e1  = expf(v1 - v0);
        const float inv = 1.0f / (1.0f + e1);

        float p = 0.f;
        if (lane == i0)      p = inv;
        else if (lane == i1) p = e1 * inv;
        probs[(size_t)g * EXPN + lane] = p;

        if (lane == 0) {
            idx_out[(size_t)g * 2 + 0] = (float)i0;
            idx_out[(size_t)g * 2 + 1] = (float)i1;
            val_out[(size_t)g * 2 + 0] = v0;
            val_out[(size_t)g * 2 + 1] = v1;
        }
    }
}

extern "C" void kernel_launch(void* const* d_in, const int* in_sizes, int n_in,
                              void* d_out, int out_size, void* d_ws, size_t ws_size,
                              hipStream_t stream) {
    const float* x     = (const float*)d_in[0];  // [B,S,D]
    const float* W     = (const float*)d_in[1];  // [E,D]
    const float* nw    = (const float*)d_in[2];  // [E]
    const float* noise = (const float*)d_in[3];  // [B,S,E]

    const int M = in_sizes[3] / EXPN;            // 16384 tokens
    const int D = in_sizes[0] / M;               // 2048
    const int wn = in_sizes[1];                  // E*D = 131072

    unsigned short* whp = (unsigned short*)d_ws;            // [E,D] bf16 hi
    unsigned short* wlp = whp + (size_t)wn;                 // [E,D] bf16 lo

    float* probs   = (float*)d_out;              // [M, E]
    float* idx_out = probs + (size_t)M * EXPN;   // [M, 2]
    float* val_out = idx_out + (size_t)M * 2;    // [M, 2]

    const int n4 = wn / 4;
    convert_w_kernel<<<(n4 + 255) / 256, 256, 0, stream>>>(W, whp, wlp, n4);

    const int grid = M / TM;                     // 1024 blocks
    moe_gate_kernel<<<grid, 256, 0, stream>>>(x, W, whp, wlp, nw, noise,
                                              probs, idx_out, val_out, D);
}

// Round 2
// 256.805 us; speedup vs baseline: 1.0777x; 1.0777x over previous
//
#include <hip/hip_runtime.h>
#include <math.h>

// TopKMoEGate via split-bf16 MFMA:
//   x = xh + xl, W = wh + wl (bf16 hi/lo); logits = xh*wh + xh*wl + xl*wh
//   (fp32-accurate to ~5e-6; wave-parallel fp64 tie-guard on top-3 candidates).
// R9: m97-style DMA staging. R8's named-register prefetch never materialized
//     (VGPR_Count=48 proves it) -> compiler sank loads to use sites -> full
//     latency exposure. Remedy: global_load_lds (compiler cannot sink the DMA;
//     __syncthreads' vmcnt(0) is the sync) + small LDS for occupancy:
//     TM=16 tokens/block, BK=32, x staged fp32 (split2 on read), W hi/lo in one
//     [64][64] bf16 tile. LDS 24.6 KB -> 6 blocks/CU (24 waves/CU). Bank
//     conflicts killed by XOR-granule swizzle applied on the per-lane GLOBAL
//     source address (LDS dest linear, read side applies the same XOR - guide
//     rule #21). 4 waves = 4 expert quarters, no K-split, 3 MFMA/chunk,
//     minimum 2-phase schedule: STAGE(next) -> COMPUTE(cur) -> barrier.

typedef __attribute__((ext_vector_type(8))) __bf16 bf16x8;
typedef __attribute__((ext_vector_type(8))) unsigned short u16x8;
typedef __attribute__((ext_vector_type(4))) float f32x4;

constexpr int EXPN = 64;   // experts
constexpr int TM   = 16;   // tokens per block
constexpr int BK   = 32;   // k per chunk

__device__ __forceinline__ void split2(float f, unsigned short& h, unsigned short& l) {
    const unsigned b = __float_as_uint(f);
    h = (unsigned short)(b >> 16);                       // bf16 hi (truncate)
    const float fh = __uint_as_float(b & 0xffff0000u);
    l = (unsigned short)(__float_as_uint(f - fh) >> 16); // bf16 lo
}

__device__ __forceinline__ bf16x8 as_bf16(u16x8 v) {
    union { u16x8 u; bf16x8 b; } c; c.u = v; return c.b;
}

// async global -> LDS DMA, 16 B per lane; LDS dest = wave-uniform base + lane*16
__device__ __forceinline__ void gload16(const void* g, void* l) {
    typedef __attribute__((address_space(1))) void gv;
    typedef __attribute__((address_space(3))) void lv;
    __builtin_amdgcn_global_load_lds((gv*)g, (lv*)l, 16, 0, 0);
}

// ---- pre-kernel: W fp32 -> wh/wl bf16 planes (same split2 numerics) ----
__global__ __launch_bounds__(256)
void convert_w_kernel(const float* __restrict__ W,
                      unsigned short* __restrict__ whp,
                      unsigned short* __restrict__ wlp, int n4)
{
    const int i = blockIdx.x * 256 + threadIdx.x;   // float4 index
    if (i >= n4) return;
    const float4 v = *(const float4*)(W + (size_t)i * 4);
    const float f[4] = {v.x, v.y, v.z, v.w};
    unsigned short h[4], l[4];
#pragma unroll
    for (int j = 0; j < 4; ++j) split2(f[j], h[j], l[j]);
    *(ushort4*)(whp + (size_t)i * 4) = make_ushort4(h[0], h[1], h[2], h[3]);
    *(ushort4*)(wlp + (size_t)i * 4) = make_ushort4(l[0], l[1], l[2], l[3]);
}

__global__ __launch_bounds__(256, 6)
void moe_gate_kernel(const float* __restrict__ x,      // [M, D]
                     const float* __restrict__ W,      // [E, D] (fp64 guard only)
                     const unsigned short* __restrict__ whp,  // [E, D] bf16 hi
                     const unsigned short* __restrict__ wlp,  // [E, D] bf16 lo
                     const float* __restrict__ nw,     // [E]
                     const float* __restrict__ noise,  // [M, E]
                     float* __restrict__ probs,        // [M, E]
                     float* __restrict__ idx_out,      // [M, 2] float-encoded
                     float* __restrict__ val_out,      // [M, 2]
                     int D)
{
    // rows are 128 B each; granule = 16 B; swizzle: slot = granule ^ (row&7)
    __shared__ float          xs[2][TM][BK];        // fp32 x tile, 4 KB
    __shared__ unsigned short ws[2][EXPN][2 * BK];  // [e][0:32]=hi,[32:64]=lo, 16 KB
    __shared__ float          ls[TM][EXPN + 1];     // logits, 4.2 KB

    const int tid  = threadIdx.x;
    const int lane = tid & 63;
    const int wv   = tid >> 6;          // expert quarter: experts [wv*16, wv*16+16)
    const int m0   = blockIdx.x * TM;

    const int fr = lane & 15;           // A row (token) / B row (expert) in frag
    const int kq = (lane >> 4) * 8;     // k sub-offset in frag (0,8,16,24)
    const int er = wv * 16 + fr;        // expert row (er&7 == fr&7)

    // ---- staging source addresses (pre-swizzled per-lane global pointers) ----
    const int sl8 = lane >> 3;          // sub-row within 1 KB inst (8 rows/inst)
    const int gl  = lane & 7;           // granule slot within row
    // W: 8 insts/chunk (8 expert-rows each), wave wv issues insts wv*2, wv*2+1
    const int j0 = wv * 2, j1 = j0 + 1;
    const int e0 = j0 * 8 + sl8, e1 = j1 * 8 + sl8;
    const int g0 = gl ^ (e0 & 7), g1 = gl ^ (e1 & 7);   // logical granule
    const unsigned short* wsrc0 = (g0 < 4)
        ? whp + (size_t)e0 * D + g0 * 8
        : wlp + (size_t)e0 * D + (g0 - 4) * 8;
    const unsigned short* wsrc1 = (g1 < 4)
        ? whp + (size_t)e1 * D + g1 * 8
        : wlp + (size_t)e1 * D + (g1 - 4) * 8;
    // x: 2 insts/chunk (8 token-rows each), issued by waves 2 and 3
    const float* xsrc = nullptr;
    if (wv >= 2) {
        const int row = (wv - 2) * 8 + sl8;
        const int gx  = gl ^ (row & 7);
        xsrc = x + (size_t)(m0 + row) * D + gx * 4;
    }

#define STAGE(b, c) {                                                        \
        gload16(wsrc0 + (size_t)(c) * BK, &ws[b][0][0] + j0 * 512);          \
        gload16(wsrc1 + (size_t)(c) * BK, &ws[b][0][0] + j1 * 512);          \
        if (wv >= 2)                                                         \
            gload16(xsrc + (size_t)(c) * BK, &xs[b][0][0] + (wv - 2) * 256); \
    }

    f32x4 acc = {0.f, 0.f, 0.f, 0.f};

#define COMPUTE(b) {                                                              \
        const char* xbp = (const char*)&xs[b][0][0];                              \
        const char* wbp = (const char*)&ws[b][0][0];                              \
        const float4 xa  = *(const float4*)(xbp + fr * 128 + (((kq >> 2)    ) ^ (fr & 7)) * 16); \
        const float4 xc  = *(const float4*)(xbp + fr * 128 + (((kq >> 2) + 1) ^ (fr & 7)) * 16); \
        const u16x8  bhv = *(const u16x8*)(wbp + er * 128 + (((kq >> 3)    ) ^ (fr & 7)) * 16); \
        const u16x8  blv = *(const u16x8*)(wbp + er * 128 + (((kq >> 3) + 4) ^ (fr & 7)) * 16); \
        const float xf[8] = {xa.x, xa.y, xa.z, xa.w, xc.x, xc.y, xc.z, xc.w};     \
        u16x8 hv, lv;                                                             \
        _Pragma("unroll")                                                         \
        for (int i_ = 0; i_ < 8; ++i_) {                                          \
            unsigned short h_, l_; split2(xf[i_], h_, l_);                        \
            hv[i_] = h_; lv[i_] = l_;                                             \
        }                                                                         \
        const bf16x8 ah = as_bf16(hv), al = as_bf16(lv);                          \
        acc = __builtin_amdgcn_mfma_f32_16x16x32_bf16(ah, as_bf16(bhv), acc, 0, 0, 0); \
        acc = __builtin_amdgcn_mfma_f32_16x16x32_bf16(ah, as_bf16(blv), acc, 0, 0, 0); \
        acc = __builtin_amdgcn_mfma_f32_16x16x32_bf16(al, as_bf16(bhv), acc, 0, 0, 0); \
    }

    const int nchunk = D / BK;          // 64
    STAGE(0, 0)
    __syncthreads();

    for (int c = 0; c < nchunk; ++c) {
        if (c & 1) {
            if (c + 1 < nchunk) STAGE(0, c + 1)
            COMPUTE(1)
        } else {
            if (c + 1 < nchunk) STAGE(1, c + 1)
            COMPUTE(0)
        }
        __syncthreads();
    }

#undef STAGE
#undef COMPUTE

    // ---- C/D layout: col = lane&15 (expert), row = (lane>>4)*4 + reg (token) ----
    const int trow = (lane >> 4) * 4;
#pragma unroll
    for (int r = 0; r < 4; ++r)
        ls[trow + r][wv * 16 + fr] = acc[r];
    __syncthreads();

    // ---- epilogue: per-token noisy top-2 + sparse softmax (lane = expert) ----
    const float nwv = nw[lane];

#pragma unroll 1
    for (int t = 0; t < 4; ++t) {
        const int tl = wv * 4 + t;       // local token
        const int g  = m0 + tl;          // global token
        const float logit = fmaf(noise[(size_t)g * EXPN + lane], nwv, ls[tl][lane]);

        float v0; int i0;
        {
            float v = logit; int ix = lane;
#pragma unroll
            for (int off = 32; off; off >>= 1) {
                const float vo = __shfl_xor(v, off);
                const int   io = __shfl_xor(ix, off);
                if (vo > v || (vo == v && io < ix)) { v = vo; ix = io; }
            }
            v0 = v; i0 = ix;
        }
        float v1; int i1;
        {
            float v = (lane == i0) ? -INFINITY : logit; int ix = lane;
#pragma unroll
            for (int off = 32; off; off >>= 1) {
                const float vo = __shfl_xor(v, off);
                const int   io = __shfl_xor(ix, off);
                if (vo > v || (vo == v && io < ix)) { v = vo; ix = io; }
            }
            v1 = v; i1 = ix;
        }
        float v2; int i2;
        {
            float v = (lane == i0 || lane == i1) ? -INFINITY : logit; int ix = lane;
#pragma unroll
            for (int off = 32; off; off >>= 1) {
                const float vo = __shfl_xor(v, off);
                const int   io = __shfl_xor(ix, off);
                if (vo > v || (vo == v && io < ix)) { v = vo; ix = io; }
            }
            v2 = v; i2 = ix;
        }

        // near-tie guard: wave-parallel fp64 recompute of the 3 candidate
        // logits (lanes stride K by 64 -> coalesced; butterfly fp64 sum).
        const float eps = 1e-3f;
        if ((v0 - v1) < eps || (v1 - v2) < eps) {
            const float* xr  = x + (size_t)g * D;
            const float* w0r = W + (size_t)i0 * D;
            const float* w1r = W + (size_t)i1 * D;
            const float* w2r = W + (size_t)i2 * D;
            double s0 = 0.0, s1 = 0.0, s2 = 0.0;
            for (int d = lane; d < D; d += 64) {
                const double xv = (double)xr[d];
                s0 += xv * (double)w0r[d];
                s1 += xv * (double)w1r[d];
                s2 += xv * (double)w2r[d];
            }
#pragma unroll
            for (int off = 32; off; off >>= 1) {
                s0 += __shfl_xor(s0, off);
                s1 += __shfl_xor(s1, off);
                s2 += __shfl_xor(s2, off);
            }
            double d0 = s0 + (double)noise[(size_t)g * EXPN + i0] * (double)nw[i0];
            double d1 = s1 + (double)noise[(size_t)g * EXPN + i1] * (double)nw[i1];
            double d2 = s2 + (double)noise[(size_t)g * EXPN + i2] * (double)nw[i2];
            // sort 3 (value desc, index asc on ties)
            #define CSWAP(va, ia, vb, ib)                                   \
                if ((vb > va) || (vb == va && ib < ia)) {                   \
                    double tv = va; va = vb; vb = tv;                       \
                    int ti = ia; ia = ib; ib = ti; }
            CSWAP(d0, i0, d1, i1)
            CSWAP(d1, i1, d2, i2)
            CSWAP(d0, i0, d1, i1)
            #undef CSWAP
            v0 = (float)d0; v1 = (float)d1;
        }

        const float e1  = expf(v1 - v0);
        const float inv = 1.0f / (1.0f + e1);

        float p = 0.f;
        if (lane == i0)      p = inv;
        else if (lane == i1) p = e1 * inv;
        probs[(size_t)g * EXPN + lane] = p;

        if (lane == 0) {
            idx_out[(size_t)g * 2 + 0] = (float)i0;
            idx_out[(size_t)g * 2 + 1] = (float)i1;
            val_out[(size_t)g * 2 + 0] = v0;
            val_out[(size_t)g * 2 + 1] = v1;
        }
    }
}

extern "C" void kernel_launch(void* const* d_in, const int* in_sizes, int n_in,
                              void* d_out, int out_size, void* d_ws, size_t ws_size,
                              hipStream_t stream) {
    const float* x     = (const float*)d_in[0];  // [B,S,D]
    const float* W     = (const float*)d_in[1];  // [E,D]
    const float* nw    = (const float*)d_in[2];  // [E]
    const float* noise = (const float*)d_in[3];  // [B,S,E]

    const int M = in_sizes[3] / EXPN;            // 16384 tokens
    const int D = in_sizes[0] / M;               // 2048
    const int wn = in_sizes[1];                  // E*D = 131072

    unsigned short* whp = (unsigned short*)d_ws;            // [E,D] bf16 hi
    unsigned short* wlp = whp + (size_t)wn;                 // [E,D] bf16 lo

    float* probs   = (float*)d_out;              // [M, E]
    float* idx_out = probs + (size_t)M * EXPN;   // [M, 2]
    float* val_out = idx_out + (size_t)M * 2;    // [M, 2]

    const int n4 = wn / 4;
    convert_w_kernel<<<(n4 + 255) / 256, 256, 0, stream>>>(W, whp, wlp, n4);

    const int grid = M / TM;                     // 1024 blocks
    moe_gate_kernel<<<grid, 256, 0, stream>>>(x, W, whp, wlp, nw, noise,
                                              probs, idx_out, val_out, D);
}

// Round 3
// 222.739 us; speedup vs baseline: 1.2426x; 1.1529x over previous
//
#include <hip/hip_runtime.h>
#include <math.h>

// TopKMoEGate via split-bf16 MFMA:
//   x = xh + xl, W = wh + wl (bf16 hi/lo); logits = xh*wh + xh*wl + xl*wh
//   (fp32-accurate to ~5e-6; wave-parallel fp64 tie-guard on top-3 candidates).
// R10: counted-vmcnt pipeline (T3+T4). R9's __syncthreads after STAGE lowered
//     to s_waitcnt vmcnt(0)+s_barrier -> drained the just-issued DMAs -> every
//     chunk exposed full load latency (4.3K cy/iter vs ~300 cy of work).
//     Fix per guide T4: raw __builtin_amdgcn_s_barrier + inline-asm
//     s_waitcnt vmcnt(3) (counted, NEVER 0 in the loop). 3 LDS buffers,
//     depth-2 prefetch: STAGE(c+2) issued at iter c, consumed at iter c+2.
//     Every wave issues exactly 3 global_load_lds per chunk (uniform vmcnt).
//     TM=32 tokens, BK=64, 8 waves = 2 token-halves x 4 expert-quarters.
//     LDS 72 KB (3 x [16KB W + 8KB x]), logits aliased post-loop -> 2 blk/CU.
//     16-granule XOR swizzle slot = g ^ (row&7) applied on pre-swizzled global
//     source AND ds_read side (both-sides rule); DMA dest stays linear.

typedef __attribute__((ext_vector_type(8))) __bf16 bf16x8;
typedef __attribute__((ext_vector_type(8))) unsigned short u16x8;
typedef __attribute__((ext_vector_type(4))) float f32x4;

constexpr int EXPN = 64;   // experts
constexpr int TM   = 32;   // tokens per block
constexpr int BK   = 64;   // k per chunk
constexpr int WBYTES = EXPN * 2 * BK * 2;          // 16384 B W tile (hi+lo)
constexpr int XBYTES = TM * BK * 4;                // 8192 B x tile
constexpr int BUFB   = WBYTES + XBYTES;            // 24576 B per buffer

__device__ __forceinline__ void split2(float f, unsigned short& h, unsigned short& l) {
    const unsigned b = __float_as_uint(f);
    h = (unsigned short)(b >> 16);                       // bf16 hi (truncate)
    const float fh = __uint_as_float(b & 0xffff0000u);
    l = (unsigned short)(__float_as_uint(f - fh) >> 16); // bf16 lo
}

__device__ __forceinline__ bf16x8 as_bf16(u16x8 v) {
    union { u16x8 u; bf16x8 b; } c; c.u = v; return c.b;
}

// async global -> LDS DMA, 16 B per lane; LDS dest = wave-uniform base + lane*16
__device__ __forceinline__ void gload16(const void* g, void* l) {
    typedef __attribute__((address_space(1))) void gv;
    typedef __attribute__((address_space(3))) void lv;
    __builtin_amdgcn_global_load_lds((gv*)g, (lv*)l, 16, 0, 0);
}

// ---- pre-kernel: W fp32 -> wh/wl bf16 planes (same split2 numerics) ----
__global__ __launch_bounds__(256)
void convert_w_kernel(const float* __restrict__ W,
                      unsigned short* __restrict__ whp,
                      unsigned short* __restrict__ wlp, int n4)
{
    const int i = blockIdx.x * 256 + threadIdx.x;   // float4 index
    if (i >= n4) return;
    const float4 v = *(const float4*)(W + (size_t)i * 4);
    const float f[4] = {v.x, v.y, v.z, v.w};
    unsigned short h[4], l[4];
#pragma unroll
    for (int j = 0; j < 4; ++j) split2(f[j], h[j], l[j]);
    *(ushort4*)(whp + (size_t)i * 4) = make_ushort4(h[0], h[1], h[2], h[3]);
    *(ushort4*)(wlp + (size_t)i * 4) = make_ushort4(l[0], l[1], l[2], l[3]);
}

__global__ __launch_bounds__(512, 4)
void moe_gate_kernel(const float* __restrict__ x,      // [M, D]
                     const float* __restrict__ W,      // [E, D] (fp64 guard only)
                     const unsigned short* __restrict__ whp,  // [E, D] bf16 hi
                     const unsigned short* __restrict__ wlp,  // [E, D] bf16 lo
                     const float* __restrict__ nw,     // [E]
                     const float* __restrict__ noise,  // [M, E]
                     float* __restrict__ probs,        // [M, E]
                     float* __restrict__ idx_out,      // [M, 2] float-encoded
                     float* __restrict__ val_out,      // [M, 2]
                     int D)
{
    // buffer b: W tile at smem + b*BUFB (64 rows x 256 B: [hi 128B | lo 128B]),
    //           x tile at smem + b*BUFB + WBYTES (32 rows x 256 B fp32)
    // 16-byte granules, 16/row; stored slot s of row r holds logical granule
    // s ^ (r & 7)  (XOR touches low 3 bits only -> hi/lo plane bit preserved)
    __shared__ __align__(16) char smem[3 * BUFB];    // 72 KB

    const int tid  = threadIdx.x;
    const int lane = tid & 63;
    const int wv   = tid >> 6;          // 0..7
    const int th   = wv >> 2;           // token half
    const int eq   = wv & 3;            // expert quarter
    const int m0   = blockIdx.x * TM;

    const int fr = lane & 15;           // A row (token) / B row (expert) in frag
    const int kq = (lane >> 4) * 8;     // k sub-offset in frag (0,8,16,24)
    const int f7 = fr & 7;

    // ---- staging sources (pre-swizzled per-lane global pointers) ----
    const int sl   = lane >> 4;         // sub-row within 1 KB inst (4 rows/inst)
    const int slot = lane & 15;         // granule slot within 256 B row
    // W: 16 insts/chunk; wave wv issues insts j0 = 2wv, j1 = 2wv+1
    const int j0 = wv * 2, j1 = j0 + 1;
    const int we0 = j0 * 4 + sl, we1 = j1 * 4 + sl;      // expert rows
    const int wg0 = slot ^ (we0 & 7), wg1 = slot ^ (we1 & 7); // logical granule
    const unsigned short* wsrc0 = ((wg0 < 8) ? whp : wlp)
                                + (size_t)we0 * D + (wg0 & 7) * 8;
    const unsigned short* wsrc1 = ((wg1 < 8) ? whp : wlp)
                                + (size_t)we1 * D + (wg1 & 7) * 8;
    // x: 8 insts/chunk; wave wv issues inst wv
    const int xrow = wv * 4 + sl;
    const int xg   = slot ^ (xrow & 7);
    const float* xsrc = x + (size_t)(m0 + xrow) * D + xg * 4;

#define STAGE(b, c) {                                                     \
        char* bb_ = smem + (b) * BUFB;                                    \
        gload16(wsrc0 + (size_t)(c) * BK, bb_ + j0 * 1024);               \
        gload16(wsrc1 + (size_t)(c) * BK, bb_ + j1 * 1024);               \
        gload16(xsrc  + (size_t)(c) * BK, bb_ + WBYTES + wv * 1024);      \
    }

    f32x4 acc = {0.f, 0.f, 0.f, 0.f};

#define COMPUTE(b) {                                                              \
        const char* wbp_ = smem + (b) * BUFB;                                     \
        const char* xbp_ = wbp_ + WBYTES;                                         \
        _Pragma("unroll")                                                         \
        for (int ks_ = 0; ks_ < 2; ++ks_) {                                       \
            const int kk_ = ks_ * 32 + kq;                                        \
            const int sx_ = (kk_ >> 2) ^ f7;      /* even logical granule */      \
            const float4 xa_ = *(const float4*)(xbp_ + (th*16+fr)*256 + sx_*16);  \
            const float4 xc_ = *(const float4*)(xbp_ + (th*16+fr)*256 + (sx_^1)*16); \
            const int gh_ = kk_ >> 3;                                             \
            const u16x8 bh_ = *(const u16x8*)(wbp_ + (eq*16+fr)*256 + (gh_ ^ f7)*16); \
            const u16x8 bl_ = *(const u16x8*)(wbp_ + (eq*16+fr)*256 + (8 + (gh_ ^ f7))*16); \
            const float xf_[8] = {xa_.x, xa_.y, xa_.z, xa_.w,                     \
                                  xc_.x, xc_.y, xc_.z, xc_.w};                    \
            u16x8 hv_, lv_;                                                       \
            _Pragma("unroll")                                                     \
            for (int i_ = 0; i_ < 8; ++i_) {                                      \
                unsigned short h_, l_; split2(xf_[i_], h_, l_);                   \
                hv_[i_] = h_; lv_[i_] = l_;                                       \
            }                                                                     \
            const bf16x8 ah_ = as_bf16(hv_), al_ = as_bf16(lv_);                  \
            acc = __builtin_amdgcn_mfma_f32_16x16x32_bf16(ah_, as_bf16(bh_), acc, 0, 0, 0); \
            acc = __builtin_amdgcn_mfma_f32_16x16x32_bf16(ah_, as_bf16(bl_), acc, 0, 0, 0); \
            acc = __builtin_amdgcn_mfma_f32_16x16x32_bf16(al_, as_bf16(bh_), acc, 0, 0, 0); \
        }                                                                         \
    }

    const int nchunk = D / BK;          // 32
    STAGE(0, 0)
    STAGE(1, 1)

    for (int c = 0; c < nchunk; ++c) {
        // counted drain: chunk c's 3 loads done, chunk c+1's 3 stay in flight
        if (c < nchunk - 1) asm volatile("s_waitcnt vmcnt(3)" ::: "memory");
        else                asm volatile("s_waitcnt vmcnt(0)" ::: "memory");
        __builtin_amdgcn_s_barrier();   // raw barrier: no vmcnt(0) drain
        if (c + 2 < nchunk) STAGE((c + 2) % 3, c + 2)
        COMPUTE(c % 3)
    }

#undef STAGE
#undef COMPUTE

    __syncthreads();   // all waves done reading buffers; safe to alias logits

    // ---- C/D layout: col = lane&15 (expert), row = (lane>>4)*4 + reg (token) ----
    float (*ls)[EXPN + 1] = (float (*)[EXPN + 1])smem;   // 32 x 65 fp32 = 8.3 KB
    const int trow = th * 16 + (lane >> 4) * 4;
#pragma unroll
    for (int r = 0; r < 4; ++r)
        ls[trow + r][eq * 16 + fr] = acc[r];
    __syncthreads();

    // ---- epilogue: per-token noisy top-2 + sparse softmax (lane = expert) ----
    const float nwv = nw[lane];

#pragma unroll 1
    for (int t = 0; t < 4; ++t) {
        const int tl = wv * 4 + t;       // local token (8 waves x 4 = 32)
        const int g  = m0 + tl;          // global token
        const float logit = fmaf(noise[(size_t)g * EXPN + lane], nwv, ls[tl][lane]);

        float v0; int i0;
        {
            float v = logit; int ix = lane;
#pragma unroll
            for (int off = 32; off; off >>= 1) {
                const float vo = __shfl_xor(v, off);
                const int   io = __shfl_xor(ix, off);
                if (vo > v || (vo == v && io < ix)) { v = vo; ix = io; }
            }
            v0 = v; i0 = ix;
        }
        float v1; int i1;
        {
            float v = (lane == i0) ? -INFINITY : logit; int ix = lane;
#pragma unroll
            for (int off = 32; off; off >>= 1) {
                const float vo = __shfl_xor(v, off);
                const int   io = __shfl_xor(ix, off);
                if (vo > v || (vo == v && io < ix)) { v = vo; ix = io; }
            }
            v1 = v; i1 = ix;
        }
        float v2; int i2;
        {
            float v = (lane == i0 || lane == i1) ? -INFINITY : logit; int ix = lane;
#pragma unroll
            for (int off = 32; off; off >>= 1) {
                const float vo = __shfl_xor(v, off);
                const int   io = __shfl_xor(ix, off);
                if (vo > v || (vo == v && io < ix)) { v = vo; ix = io; }
            }
            v2 = v; i2 = ix;
        }

        // near-tie guard: wave-parallel fp64 recompute of the 3 candidate
        // logits (lanes stride K by 64 -> coalesced; butterfly fp64 sum).
        const float eps = 1e-3f;
        if ((v0 - v1) < eps || (v1 - v2) < eps) {
            const float* xr  = x + (size_t)g * D;
            const float* w0r = W + (size_t)i0 * D;
            const float* w1r = W + (size_t)i1 * D;
            const float* w2r = W + (size_t)i2 * D;
            double s0 = 0.0, s1 = 0.0, s2 = 0.0;
            for (int d = lane; d < D; d += 64) {
                const double xv = (double)xr[d];
                s0 += xv * (double)w0r[d];
                s1 += xv * (double)w1r[d];
                s2 += xv * (double)w2r[d];
            }
#pragma unroll
            for (int off = 32; off; off >>= 1) {
                s0 += __shfl_xor(s0, off);
                s1 += __shfl_xor(s1, off);
                s2 += __shfl_xor(s2, off);
            }
            double d0 = s0 + (double)noise[(size_t)g * EXPN + i0] * (double)nw[i0];
            double d1 = s1 + (double)noise[(size_t)g * EXPN + i1] * (double)nw[i1];
            double d2 = s2 + (double)noise[(size_t)g * EXPN + i2] * (double)nw[i2];
            // sort 3 (value desc, index asc on ties)
            #define CSWAP(va, ia, vb, ib)                                   \
                if ((vb > va) || (vb == va && ib < ia)) {                   \
                    double tv = va; va = vb; vb = tv;                       \
                    int ti = ia; ia = ib; ib = ti; }
            CSWAP(d0, i0, d1, i1)
            CSWAP(d1, i1, d2, i2)
            CSWAP(d0, i0, d1, i1)
            #undef CSWAP
            v0 = (float)d0; v1 = (float)d1;
        }

        const float e1  = expf(v1 - v0);
        const float inv = 1.0f / (1.0f + e1);

        float p = 0.f;
        if (lane == i0)      p = inv;
        else if (lane == i1) p = e1 * inv;
        probs[(size_t)g * EXPN + lane] = p;

        if (lane == 0) {
            idx_out[(size_t)g * 2 + 0] = (float)i0;
            idx_out[(size_t)g * 2 + 1] = (float)i1;
            val_out[(size_t)g * 2 + 0] = v0;
            val_out[(size_t)g * 2 + 1] = v1;
        }
    }
}

extern "C" void kernel_launch(void* const* d_in, const int* in_sizes, int n_in,
                              void* d_out, int out_size, void* d_ws, size_t ws_size,
                              hipStream_t stream) {
    const float* x     = (const float*)d_in[0];  // [B,S,D]
    const float* W     = (const float*)d_in[1];  // [E,D]
    const float* nw    = (const float*)d_in[2];  // [E]
    const float* noise = (const float*)d_in[3];  // [B,S,E]

    const int M = in_sizes[3] / EXPN;            // 16384 tokens
    const int D = in_sizes[0] / M;               // 2048
    const int wn = in_sizes[1];                  // E*D = 131072

    unsigned short* whp = (unsigned short*)d_ws;            // [E,D] bf16 hi
    unsigned short* wlp = whp + (size_t)wn;                 // [E,D] bf16 lo

    float* probs   = (float*)d_out;              // [M, E]
    float* idx_out = probs + (size_t)M * EXPN;   // [M, 2]
    float* val_out = idx_out + (size_t)M * 2;    // [M, 2]

    const int n4 = wn / 4;
    convert_w_kernel<<<(n4 + 255) / 256, 256, 0, stream>>>(W, whp, wlp, n4);

    const int grid = M / TM;                     // 512 blocks
    moe_gate_kernel<<<grid, 512, 0, stream>>>(x, W, whp, wlp, nw, noise,
                                              probs, idx_out, val_out, D);
}